// Round 12
// baseline (656.586 us; speedup 1.0000x reference)
//
#include <hip/hip_runtime.h>
#include <hip/hip_bf16.h>
#include <math.h>
#include <stdint.h>
#include <stddef.h>

// Problem constants (fixed by the reference)
#define TB 8
#define TT 8192
#define DD 256
#define NR (TB * TT)   // 65536 rows
#define HH 1024        // 4*D
#define LL 3

typedef unsigned short ushort_t;
typedef __attribute__((ext_vector_type(8))) short short8;   // 8 bf16 in 4 VGPRs
typedef __attribute__((ext_vector_type(4))) float floatx4;  // MFMA accumulator

__device__ __forceinline__ float bf2f(ushort_t u) {
  union { unsigned int i; float f; } x; x.i = ((unsigned int)u) << 16; return x.f;
}
__device__ __forceinline__ ushort_t f2bf(float f) {
  union { float f; unsigned int i; } x; x.f = f;
  unsigned int r = x.i + 0x7fffu + ((x.i >> 16) & 1u);  // RNE
  return (ushort_t)(r >> 16);
}
__device__ __forceinline__ float ld_in(const void* p, size_t i, int isf) {
  return isf ? ((const float*)p)[i] : bf2f(((const ushort_t*)p)[i]);
}
// tanh-form GELU via hardware exp (~8 VALU insts; |err| vs erf-gelu ~3e-4)
__device__ __forceinline__ float gelu_f(float v) {
  const float y = v * (0.7978845608028654f + 0.035677408136300125f * v * v);
  const float e = __expf(-2.0f * y);
  return v * __builtin_amdgcn_rcpf(1.0f + e);
}
__device__ __forceinline__ int deg_of(int t) {
  return (t >= 1) + (t >= 5) + (t >= 15) + (t >= 30)
       + (t < TT - 1) + (t < TT - 5) + (t < TT - 15) + (t < TT - 30);
}
// async global->LDS, 16B per lane; lds ptr must be wave-uniform base
__device__ __forceinline__ void gl_lds16(const ushort_t* g, void* l) {
  __builtin_amdgcn_global_load_lds(
      (const __attribute__((address_space(1))) unsigned int*)(g),
      (__attribute__((address_space(3))) unsigned int*)(l), 16, 0, 0);
}
// bijective XCD swizzle (m204 form; requires nwg % 8 == 0)
__device__ __forceinline__ int xcd_swz(int lin, int nwg) {
  const int q = nwg >> 3;
  return (lin & 7) * q + (lin >> 3);
}
// T2 XOR swizzles: permute 16B chunks within a row (bijective per row)
__device__ __forceinline__ int swz128(int row, int bytecol) {
  return row * 128 + (bytecol ^ ((row & 7) << 4));
}
__device__ __forceinline__ int swz64(int row, int bytecol) {
  return row * 64 + (bytecol ^ ((row & 3) << 4));
}
#define WAIT_VM0()  asm volatile("s_waitcnt vmcnt(0)" ::: "memory")
#define WAIT_VM4()  asm volatile("s_waitcnt vmcnt(4)" ::: "memory")
#define WAIT_LGKM0() asm volatile("s_waitcnt lgkmcnt(0)" ::: "memory")

// -------- dtype probe: fp32 (1) vs bf16 (0) from x's bit patterns --------
__global__ void k_probe(const void* __restrict__ x, int* __restrict__ flag) {
  if (threadIdx.x == 0 && blockIdx.x == 0) {
    const float* fb = (const float*)x;
    int okf = 0;
    for (int i = 0; i < 128; ++i) {
      const float av = fabsf(fb[i]);
      if (av > 1e-6f && av < 100.f) okf++;
    }
    *flag = (okf >= 115) ? 1 : 0;
  }
}

// ==================== phase 0: weight transposes + x conversion ============
// one 32x32 transpose tile; b<192: conv_w[i]; b<448: w1; else: w2
__device__ __forceinline__ void transpose_tile(
    char* smem_, const void* cw, const void* w1, const void* w2,
    ushort_t* cwT, ushort_t* w1T, ushort_t* w2T, int isf, int b, int tid) {
  ushort_t (*tile)[33] = (ushort_t(*)[33])smem_;
  const void* src; ushort_t* dst; int R, C, bx, by; size_t row0;
  if (b < 192) {
    const int i = b >> 6, t = b & 63;
    src = cw; dst = cwT + (size_t)i * DD * DD; row0 = (size_t)i * DD;
    R = DD; C = DD; bx = (t & 7) * 32; by = (t >> 3) * 32;
  } else if (b < 448) {
    const int t = b - 192;
    src = w1; dst = w1T; row0 = 0; R = DD; C = HH;
    bx = (t & 31) * 32; by = (t >> 5) * 32;
  } else {
    const int t = b - 448;
    src = w2; dst = w2T; row0 = 0; R = HH; C = DD;
    bx = (t & 7) * 32; by = (t >> 3) * 32;
  }
  const int tx = tid & 31, ty = tid >> 5;
  __syncthreads();
  for (int i = ty; i < 32; i += 8)
    tile[i][tx] = f2bf(ld_in(src, (row0 + by + i) * (size_t)C + bx + tx, isf));
  __syncthreads();
  for (int i = ty; i < 32; i += 8)
    dst[(size_t)(bx + i) * R + by + tx] = tile[tx][i];
}

// 512 blocks: blocks 0..191 do transpose tiles (bid, bid+512); 192..511 do
// tile bid.  All blocks convert their 1/512 slice of x.
__global__ __launch_bounds__(256) void k_phase0(
    const void* __restrict__ x, ushort_t* __restrict__ xA,
    const void* __restrict__ cw, const void* __restrict__ w1,
    const void* __restrict__ w2, ushort_t* __restrict__ cwT,
    ushort_t* __restrict__ w1T, ushort_t* __restrict__ w2T,
    const int* __restrict__ flag) {
  __shared__ alignas(16) char smem[4224];
  const int isf = *flag;
  const int bid = blockIdx.x, tid = threadIdx.x;
  transpose_tile(smem, cw, w1, w2, cwT, w1T, w2T, isf, bid, tid);
  if (bid < 192)
    transpose_tile(smem, cw, w1, w2, cwT, w1T, w2T, isf, 512 + bid, tid);
  // cvt: 8192 ushort4 per block (NR*DD/4 / 512)
  const size_t c0 = (size_t)bid * 8192 + tid;
  if (isf) {
    const float4* xf = (const float4*)x;
    ushort4* xo = (ushort4*)xA;
#pragma unroll
    for (int i = 0; i < 32; ++i) {
      const float4 f = xf[c0 + i * 256];
      ushort4 u; u.x = f2bf(f.x); u.y = f2bf(f.y); u.z = f2bf(f.z); u.w = f2bf(f.w);
      xo[c0 + i * 256] = u;
    }
  } else {
#pragma unroll
    for (int i = 0; i < 32; ++i)
      ((ushort4*)xA)[c0 + i * 256] = ((const ushort4*)x)[c0 + i * 256];
  }
}

// ==================== fused agg + conv layer ====================
// 64 rows x 256 cols, 4 waves (64-col quarter each).  Round 12: agg phase
// is round-6 VERBATIM (fully parallel, one barrier); only the B-staging
// shrinks to per-wave [64][32] slices (8 K-steps of 16 MFMAs, per-wave
// vmcnt sync, no new block barriers).  LDS 68.1->51.7KB -> 3 blocks/CU.
// xout store back to PLAIN (round-11 nt-store killed inter-layer L2 reuse).
__global__ __launch_bounds__(256, 3) void k_conv_fused(
    const ushort_t* __restrict__ xin, ushort_t* __restrict__ xout,
    const ushort_t* __restrict__ Bt, const void* __restrict__ bias,
    size_t boff, const void* __restrict__ g, const void* __restrict__ bn,
    size_t goff, const int* __restrict__ flag) {
  // bytes: scr 2560 | aggA 32768 | lB 4x4096 -> 51712 (3 blocks/CU)
  __shared__ alignas(16) char smem[51712];
  float* scr    = (float*)smem;
  float* part   = scr;          // [4][64]
  float* partsq = scr + 256;    // [4][64]
  float* smu    = scr + 512;    // [64]
  float* srs    = scr + 576;    // [64]
  char* aggA    = smem + 2560;  // [4 kc][64][64] swizzled
  char* rt      = smem + 2560;  // [64][264] elems (epilogue alias, 33.8KB)
  const int isf = *flag;

  const int tid  = threadIdx.x;
  const int lane = tid & 63;
  const int l16  = lane & 15;
  const int quad = lane >> 4;
  const int w    = tid >> 6;          // wave id = col quarter
  const int m0   = xcd_swz(blockIdx.x, gridDim.x) * 64;

  char* lB = smem + 35328 + w * 4096; // this wave's B slice [64][32] swz64

  // per-wave B staging, 32-k sub-slice s = kc*2+ks (ffn-B2 stager pattern)
  const int sr4 = lane >> 2;                    // 0..15
  const int ss4 = (lane & 3) ^ (sr4 & 3);       // inverse swz64 source seg
  auto stageB = [&](int s) {
    const int kc = s >> 1, ks = s & 1;
#pragma unroll
    for (int i = 0; i < 4; ++i)
      gl_lds16(Bt + (size_t)(w * 64 + i * 16 + sr4) * DD +
                   kc * 64 + ks * 32 + ss4 * 8,
               lB + i * 1024);
  };
  stageB(0);   // in flight during the whole agg phase

  // ---- phase 1: aggregation into aggA (round-6 verbatim) ----
  const int tbase = m0 & (TT - 1);   // 64-row tile never crosses a batch
  const bool interior = (tbase >= 60) && (tbase <= TT - 124);
  const int koffs[8] = {-30, -15, -5, -1, 1, 5, 15, 30};
#pragma unroll
  for (int j = 0; j < 8; ++j) {
    const int id = j * 256 + tid;
    const int r = id >> 5, c = id & 31;
    const ushort_t* base = xin + (size_t)(m0 + r) * DD + c * 8;
    float s[8] = {0.f, 0.f, 0.f, 0.f, 0.f, 0.f, 0.f, 0.f};
    if (interior) {
#pragma unroll
      for (int e = 0; e < 8; ++e) {
        const short8 u = *(const short8*)(base + (ptrdiff_t)koffs[e] * DD);
#pragma unroll
        for (int q2 = 0; q2 < 8; ++q2) s[q2] += bf2f((ushort_t)u[q2]);
      }
#pragma unroll
      for (int q2 = 0; q2 < 8; ++q2) s[q2] *= 0.125f;
    } else {
      const int t = tbase + r;
      const float di = rsqrtf((float)deg_of(t));
#pragma unroll
      for (int e = 0; e < 8; ++e) {
        const int t2 = t + koffs[e];
        if ((unsigned)t2 < (unsigned)TT) {
          const float wgt = di * rsqrtf((float)deg_of(t2));
          const short8 u = *(const short8*)(base + (ptrdiff_t)koffs[e] * DD);
#pragma unroll
          for (int q2 = 0; q2 < 8; ++q2) s[q2] += wgt * bf2f((ushort_t)u[q2]);
        }
      }
    }
    short8 o;
#pragma unroll
    for (int q2 = 0; q2 < 8; ++q2) o[q2] = (short)f2bf(s[q2]);
    *(short8*)(aggA + (c >> 3) * 8192 + swz128(r, (c & 7) * 16)) = o;
  }
  WAIT_LGKM0();
  __builtin_amdgcn_s_barrier();      // aggA visible (raw: B stays in flight)
  __builtin_amdgcn_sched_barrier(0);

  // ---- phase 2: K-loop, 8 x 16 MFMAs, per-wave staging sync ----
  floatx4 acc[4][4];
#pragma unroll
  for (int i = 0; i < 4; ++i)
#pragma unroll
    for (int j = 0; j < 4; ++j) acc[i][j] = {0.f, 0.f, 0.f, 0.f};

#pragma unroll
  for (int s = 0; s < 8; ++s) {
    WAIT_VM0();                      // this sub-slice arrived
    const int kc = s >> 1, ks = s & 1;
    short8 af[4], bfr[4];
#pragma unroll
    for (int mt = 0; mt < 4; ++mt)
      af[mt] = *(const short8*)(aggA + kc * 8192 +
                 swz128(mt * 16 + l16, ks * 64 + quad * 16));
#pragma unroll
    for (int nt = 0; nt < 4; ++nt)
      bfr[nt] = *(const short8*)(lB + swz64(nt * 16 + l16, quad * 16));
    WAIT_LGKM0();                    // frag reads retired before overwrite
    __builtin_amdgcn_sched_barrier(0);
    if (s < 7) stageB(s + 1);        // prefetch hides under MFMAs below
#pragma unroll
    for (int mt = 0; mt < 4; ++mt)
#pragma unroll
      for (int nt = 0; nt < 4; ++nt)
        acc[mt][nt] = __builtin_amdgcn_mfma_f32_16x16x32_bf16(
            af[mt], bfr[nt], acc[mt][nt], 0, 0, 0);
  }

  // ---- phase 3: gelu+bias, block LN, residual (round-6 verbatim) ----
#pragma unroll
  for (int nt = 0; nt < 4; ++nt) {
    const float bv = ld_in(bias, boff + w * 64 + nt * 16 + l16, isf);
#pragma unroll
    for (int mt = 0; mt < 4; ++mt)
#pragma unroll
      for (int r = 0; r < 4; ++r)
        acc[mt][nt][r] = gelu_f(acc[mt][nt][r] + bv);
  }
#pragma unroll
  for (int mt = 0; mt < 4; ++mt) {
#pragma unroll
    for (int r = 0; r < 4; ++r) {
      float p = 0.f, q = 0.f;
#pragma unroll
      for (int nt = 0; nt < 4; ++nt) {
        const float v = acc[mt][nt][r];
        p += v; q += v * v;
      }
#pragma unroll
      for (int o = 8; o > 0; o >>= 1) {
        p += __shfl_xor(p, o, 64);
        q += __shfl_xor(q, o, 64);
      }
      if (l16 == 0) {
        const int rowloc = mt * 16 + quad * 4 + r;
        part[w * 64 + rowloc] = p;
        partsq[w * 64 + rowloc] = q;
      }
    }
  }
  __syncthreads();
  if (tid < 64) {
    const float s  = part[tid] + part[64 + tid] + part[128 + tid] + part[192 + tid];
    const float sq = partsq[tid] + partsq[64 + tid] + partsq[128 + tid] + partsq[192 + tid];
    const float mu = s * (1.0f / DD);
    const float var = sq * (1.0f / DD) - mu * mu;
    smu[tid] = mu;
    srs[tid] = rsqrtf(var + 1e-5f);
  }
  __syncthreads();

  // stage LN output into padded tile rt[64][264] (aliases aggA/lB, now dead)
#pragma unroll
  for (int nt = 0; nt < 4; ++nt) {
    const int col = w * 64 + nt * 16 + l16;
    const float gv = ld_in(g, goff + col, isf);
    const float bnv = ld_in(bn, goff + col, isf);
#pragma unroll
    for (int mt = 0; mt < 4; ++mt) {
#pragma unroll
      for (int r = 0; r < 4; ++r) {
        const int rowloc = mt * 16 + quad * 4 + r;
        *(ushort_t*)(rt + (rowloc * 264 + col) * 2) =
            f2bf((acc[mt][nt][r] - smu[rowloc]) * srs[rowloc] * gv + bnv);
      }
    }
  }
  __syncthreads();

  // coalesced: xout = xin + rt (plain store: next layer re-reads via L2)
#pragma unroll
  for (int i = 0; i < 8; ++i) {
    const int ch = tid + i * 256;        // 16B chunk id; 32 chunks/row
    const int row = ch >> 5, sg = ch & 31;
    const short8 xv = *(const short8*)(xin + (size_t)(m0 + row) * DD + sg * 8);
    const short8 rv = *(const short8*)(rt + (row * 264 + sg * 8) * 2);
    short8 ov;
#pragma unroll
    for (int j = 0; j < 8; ++j)
      ov[j] = (short)f2bf(bf2f((ushort_t)xv[j]) + bf2f((ushort_t)rv[j]));
    *(short8*)(xout + (size_t)(m0 + row) * DD + sg * 8) = ov;
  }
}

// ==================== fused FFN (counted-vmcnt pipeline, round-10/11) ======
// 64 rows/block, 256 thr (4 waves), 80KB LDS -> exactly 2 blocks/CU.
// 64-step per-wave weight pipeline, double-buffered, vmcnt(4) counted waits.
// dout stores non-temporal (never re-read); setprio around MFMA clusters.
__global__ __launch_bounds__(256, 2) void k_ffn(
    const ushort_t* __restrict__ xb, const ushort_t* __restrict__ w1T,
    const ushort_t* __restrict__ w2T, const void* __restrict__ gff,
    const void* __restrict__ bff, const void* __restrict__ b1,
    const void* __restrict__ b2, void* __restrict__ dout,
    const int* __restrict__ flag) {
  __shared__ alignas(16) char smem[81920];
  char* An = smem;            // [4 kc][64][64] LN(x), swizzled, 32KB
  char* Zs = smem + 32768;    // [2 kc2][64][64] z, swizzled, 16KB
  char* Rs = smem;            // resid [64][256] linear (aliases An, epilogue)
  const int isf = *flag;

  const int tid  = threadIdx.x;
  const int lane = tid & 63;
  const int l16  = lane & 15;
  const int quad = lane >> 4;
  const int w    = tid >> 6;      // 0..3
  const int m0   = xcd_swz(blockIdx.x, gridDim.x) * 64;
  char* Bw0 = smem + 49152 + w * 8192;   // this wave's dbuf: +0 / +4096

  const int sr8 = lane >> 3;                    // B1: [32][64] tile, 4 issues
  const int ss8 = (lane & 7) ^ (sr8 & 7);
  const int sr4 = lane >> 2;                    // B2: [64][32] tile, 4 issues
  const int ss4 = (lane & 3) ^ (sr4 & 3);

  // stage pipeline slice g (g = n1*8 + s; s<4: B1 kc=s, s>=4: B2 sub s-4)
  auto stage_g = [&](int gg) {
    if (gg >= 64) return;
    const int n1 = gg >> 3, s = gg & 7;
    char* dst = Bw0 + (gg & 1) * 4096;
    if (s < 4) {
#pragma unroll
      for (int i = 0; i < 4; ++i)
        gl_lds16(w1T + (size_t)(n1 * 128 + w * 32 + i * 8 + sr8) * DD +
                     s * 64 + ss8 * 8,
                 dst + i * 1024);
    } else {
      const int kc2 = (s - 4) >> 1, ks = (s - 4) & 1;
#pragma unroll
      for (int i = 0; i < 4; ++i)
        gl_lds16(w2T + (size_t)(w * 64 + i * 16 + sr4) * HH +
                     n1 * 128 + kc2 * 64 + ks * 32 + ss4 * 8,
                 dst + i * 1024);
    }
  };

  stage_g(0);      // slices 0,1 land during the LN prologue
  stage_g(1);

  // ---- LN prologue: 32-lane group per row, 8 passes ----
  const int sg = tid & 31;
  float gffv[8], bffv[8];
#pragma unroll
  for (int j = 0; j < 8; ++j) {
    gffv[j] = ld_in(gff, sg * 8 + j, isf);
    bffv[j] = ld_in(bff, sg * 8 + j, isf);
  }
#pragma unroll
  for (int i = 0; i < 8; ++i) {
    const int row = (tid + i * 256) >> 5;    // 0..63
    const short8 xv = *(const short8*)(xb + (size_t)(m0 + row) * DD + sg * 8);
    float v[8], ps = 0.f, pq = 0.f;
#pragma unroll
    for (int j = 0; j < 8; ++j) {
      v[j] = bf2f((ushort_t)xv[j]); ps += v[j]; pq += v[j] * v[j];
    }
#pragma unroll
    for (int o = 16; o > 0; o >>= 1) {
      ps += __shfl_xor(ps, o, 64);
      pq += __shfl_xor(pq, o, 64);
    }
    const float mu = ps * (1.0f / DD);
    const float rs = rsqrtf(pq * (1.0f / DD) - mu * mu + 1e-5f);
    short8 o8;
#pragma unroll
    for (int j = 0; j < 8; ++j)
      o8[j] = (short)f2bf((v[j] - mu) * rs * gffv[j] + bffv[j]);
    *(short8*)(An + (sg >> 3) * 8192 + swz128(row, (sg & 7) * 16)) = o8;
  }
  WAIT_LGKM0();
  __builtin_amdgcn_s_barrier();       // An visible (raw: slices in flight)
  __builtin_amdgcn_sched_barrier(0);

  floatx4 acc2[4][4];
#pragma unroll
  for (int i = 0; i < 4; ++i)
#pragma unroll
    for (int j = 0; j < 4; ++j) acc2[i][j] = {0.f, 0.f, 0.f, 0.f};

  for (int n1 = 0; n1 < 8; ++n1) {
    // b1 params for this chunk (issued early; retire in-order before slices)
    const float b1v0 = ld_in(b1, n1 * 128 + w * 32 + l16, isf);
    const float b1v1 = ld_in(b1, n1 * 128 + w * 32 + 16 + l16, isf);

    // ---- gemm1: z[64][128-chunk]; wave computes its 32 cols ----
    floatx4 acc1[4][2];
#pragma unroll
    for (int i = 0; i < 4; ++i)
#pragma unroll
      for (int j = 0; j < 2; ++j) acc1[i][j] = {0.f, 0.f, 0.f, 0.f};

#pragma unroll
    for (int kc = 0; kc < 4; ++kc) {
      const int gs = n1 * 8 + kc;
      WAIT_VM4();                      // slice gs landed; gs+1 in flight
      const char* Bw = Bw0 + (gs & 1) * 4096;
      short8 af0[4], af1[4], bq0[2], bq1[2];
#pragma unroll
      for (int mt = 0; mt < 4; ++mt) {
        af0[mt] = *(const short8*)(An + kc * 8192 +
                     swz128(mt * 16 + l16, quad * 16));
        af1[mt] = *(const short8*)(An + kc * 8192 +
                     swz128(mt * 16 + l16, 64 + quad * 16));
      }
#pragma unroll
      for (int nt = 0; nt < 2; ++nt) {
        bq0[nt] = *(const short8*)(Bw + swz128(nt * 16 + l16, quad * 16));
        bq1[nt] = *(const short8*)(Bw + swz128(nt * 16 + l16, 64 + quad * 16));
      }
      WAIT_LGKM0();                    // frag reads retired
      __builtin_amdgcn_sched_barrier(0);
      stage_g(gs + 2);                 // refill this buffer, 2 ahead
      __builtin_amdgcn_s_setprio(1);
#pragma unroll
      for (int mt = 0; mt < 4; ++mt)
#pragma unroll
        for (int nt = 0; nt < 2; ++nt)
          acc1[mt][nt] = __builtin_amdgcn_mfma_f32_16x16x32_bf16(
              af0[mt], bq0[nt], acc1[mt][nt], 0, 0, 0);
#pragma unroll
      for (int mt = 0; mt < 4; ++mt)
#pragma unroll
        for (int nt = 0; nt < 2; ++nt)
          acc1[mt][nt] = __builtin_amdgcn_mfma_f32_16x16x32_bf16(
              af1[mt], bq1[nt], acc1[mt][nt], 0, 0, 0);
      __builtin_amdgcn_s_setprio(0);
    }

    // ---- gelu + b1 -> z (swizzled scalar writes) ----
#pragma unroll
    for (int nt = 0; nt < 2; ++nt) {
      const int col = w * 32 + nt * 16 + l16;           // 0..127 in chunk
      const float b1v = nt ? b1v1 : b1v0;
#pragma unroll
      for (int mt = 0; mt < 4; ++mt)
#pragma unroll
        for (int r = 0; r < 4; ++r) {
          const int row = mt * 16 + quad * 4 + r;
          *(ushort_t*)(Zs + (col >> 6) * 8192 + swz128(row, (col & 63) * 2)) =
              f2bf(gelu_f(acc1[mt][nt][r] + b1v));
        }
    }
    WAIT_LGKM0();
    __builtin_amdgcn_s_barrier();      // z visible (raw: slices in flight)
    __builtin_amdgcn_sched_barrier(0);

    // ---- gemm2 partial: acc2 += z @ W2-slice ----
#pragma unroll
    for (int s2 = 0; s2 < 4; ++s2) {
      const int gs = n1 * 8 + 4 + s2;
      const int kc2 = s2 >> 1, ks = s2 & 1;
      if (gs == 63) { WAIT_VM0(); } else { WAIT_VM4(); }
      const char* Bw = Bw0 + (gs & 1) * 4096;
      short8 af[4], bfr[4];
#pragma unroll
      for (int mt = 0; mt < 4; ++mt)
        af[mt] = *(const short8*)(Zs + kc2 * 8192 +
                   swz128(mt * 16 + l16, ks * 64 + quad * 16));
#pragma unroll
      for (int nt = 0; nt < 4; ++nt)
        bfr[nt] = *(const short8*)(Bw + swz64(nt * 16 + l16, quad * 16));
      WAIT_LGKM0();
      __builtin_amdgcn_sched_barrier(0);
      stage_g(gs + 2);
      __builtin_amdgcn_s_setprio(1);
#pragma unroll
      for (int mt = 0; mt < 4; ++mt)
#pragma unroll
        for (int nt = 0; nt < 4; ++nt)
          acc2[mt][nt] = __builtin_amdgcn_mfma_f32_16x16x32_bf16(
              af[mt], bfr[nt], acc2[mt][nt], 0, 0, 0);
      __builtin_amdgcn_s_setprio(0);
    }
    __builtin_amdgcn_s_barrier();      // z consumed; next n1 may overwrite
    __builtin_amdgcn_sched_barrier(0);
  }

  // ---- epilogue: stage resid into Rs (An dead; vm drained at gs=63),
  // add b2, non-temporal store ----
#pragma unroll
  for (int i = 0; i < 8; ++i)          // [64][256] bf16 = 32KB, linear
    gl_lds16(xb + (size_t)(m0 + ((i * 256 + tid) >> 5)) * DD +
                 ((i * 256 + tid) & 31) * 8,
             Rs + i * 4096 + w * 1024);
  __syncthreads();                     // full drain + barrier

#pragma unroll
  for (int nt = 0; nt < 4; ++nt) {
    const int col = w * 64 + nt * 16 + l16;
    const float b2v = ld_in(b2, col, isf);
#pragma unroll
    for (int mt = 0; mt < 4; ++mt) {
#pragma unroll
      for (int r = 0; r < 4; ++r) {
        const int lr = mt * 16 + quad * 4 + r;
        const float v = acc2[mt][nt][r] + b2v +
                        bf2f(*(const ushort_t*)(Rs + lr * 512 + col * 2));
        const size_t idx = (size_t)(m0 + lr) * DD + col;
        if (isf) __builtin_nontemporal_store(v, &((float*)dout)[idx]);
        else     __builtin_nontemporal_store(f2bf(v), &((ushort_t*)dout)[idx]);
      }
    }
  }
}

extern "C" void kernel_launch(void* const* d_in, const int* in_sizes, int n_in,
                              void* d_out, int out_size, void* d_ws, size_t ws_size,
                              hipStream_t stream) {
  const void* x      = d_in[0];
  const void* conv_w = d_in[3];
  const void* conv_b = d_in[4];
  const void* norm_g = d_in[5];
  const void* norm_b = d_in[6];
  const void* nff_g  = d_in[7];
  const void* nff_b  = d_in[8];
  const void* w1     = d_in[9];
  const void* b1     = d_in[10];
  const void* w2     = d_in[11];
  const void* b2     = d_in[12];
  (void)in_sizes; (void)n_in; (void)out_size; (void)ws_size;

  char* ws = (char*)d_ws;
  int*      flag = (int*)ws;      ws += 16;
  ushort_t* xA   = (ushort_t*)ws; ws += (size_t)NR * DD * 2;
  ushort_t* xB   = (ushort_t*)ws; ws += (size_t)NR * DD * 2;
  ushort_t* cwT  = (ushort_t*)ws; ws += (size_t)LL * DD * DD * 2;
  ushort_t* w1T  = (ushort_t*)ws; ws += (size_t)DD * HH * 2;
  ushort_t* w2T  = (ushort_t*)ws; ws += (size_t)HH * DD * 2;

  k_probe<<<1, 64, 0, stream>>>(x, flag);
  k_phase0<<<512, 256, 0, stream>>>(x, xA, conv_w, w1, w2, cwT, w1T, w2T,
                                    flag);

  // conv layers ping-pong xA <-> xB; final state lands in xB
  k_conv_fused<<<NR / 64, 256, 0, stream>>>(
      xA, xB, cwT, conv_b, 0, norm_g, norm_b, 0, flag);
  k_conv_fused<<<NR / 64, 256, 0, stream>>>(
      xB, xA, cwT + (size_t)DD * DD, conv_b, DD, norm_g, norm_b, DD, flag);
  k_conv_fused<<<NR / 64, 256, 0, stream>>>(
      xA, xB, cwT + (size_t)2 * DD * DD, conv_b, 2 * DD, norm_g, norm_b,
      2 * DD, flag);

  // fused FFN: LN + GEMM1 + GELU + GEMM2 + residual, one launch
  k_ffn<<<NR / 64, 256, 0, stream>>>(
      xB, w1T, w2T, nff_g, nff_b, b1, b2, d_out, flag);
}

// Round 13
// 626.097 us; speedup vs baseline: 1.0487x; 1.0487x over previous
//
#include <hip/hip_runtime.h>
#include <hip/hip_bf16.h>
#include <math.h>
#include <stdint.h>
#include <stddef.h>

// Problem constants (fixed by the reference)
#define TB 8
#define TT 8192
#define DD 256
#define NR (TB * TT)   // 65536 rows
#define HH 1024        // 4*D
#define LL 3

typedef unsigned short ushort_t;
typedef __attribute__((ext_vector_type(8))) short short8;   // 8 bf16 in 4 VGPRs
typedef __attribute__((ext_vector_type(4))) float floatx4;  // MFMA accumulator

__device__ __forceinline__ float bf2f(ushort_t u) {
  union { unsigned int i; float f; } x; x.i = ((unsigned int)u) << 16; return x.f;
}
__device__ __forceinline__ ushort_t f2bf(float f) {
  union { float f; unsigned int i; } x; x.f = f;
  unsigned int r = x.i + 0x7fffu + ((x.i >> 16) & 1u);  // RNE
  return (ushort_t)(r >> 16);
}
__device__ __forceinline__ float ld_in(const void* p, size_t i, int isf) {
  return isf ? ((const float*)p)[i] : bf2f(((const ushort_t*)p)[i]);
}
// tanh-form GELU via hardware exp (~8 VALU insts; |err| vs erf-gelu ~3e-4)
__device__ __forceinline__ float gelu_f(float v) {
  const float y = v * (0.7978845608028654f + 0.035677408136300125f * v * v);
  const float e = __expf(-2.0f * y);
  return v * __builtin_amdgcn_rcpf(1.0f + e);
}
__device__ __forceinline__ int deg_of(int t) {
  return (t >= 1) + (t >= 5) + (t >= 15) + (t >= 30)
       + (t < TT - 1) + (t < TT - 5) + (t < TT - 15) + (t < TT - 30);
}
// async global->LDS, 16B per lane; lds ptr must be wave-uniform base
__device__ __forceinline__ void gl_lds16(const ushort_t* g, void* l) {
  __builtin_amdgcn_global_load_lds(
      (const __attribute__((address_space(1))) unsigned int*)(g),
      (__attribute__((address_space(3))) unsigned int*)(l), 16, 0, 0);
}
// bijective XCD swizzle (m204 form; requires nwg % 8 == 0)
__device__ __forceinline__ int xcd_swz(int lin, int nwg) {
  const int q = nwg >> 3;
  return (lin & 7) * q + (lin >> 3);
}
// T2 XOR swizzles: permute 16B chunks within a row (bijective per row)
__device__ __forceinline__ int swz128(int row, int bytecol) {
  return row * 128 + (bytecol ^ ((row & 7) << 4));
}
__device__ __forceinline__ int swz64(int row, int bytecol) {
  return row * 64 + (bytecol ^ ((row & 3) << 4));
}
#define WAIT_VM0()  asm volatile("s_waitcnt vmcnt(0)" ::: "memory")
#define WAIT_VM4()  asm volatile("s_waitcnt vmcnt(4)" ::: "memory")
#define WAIT_LGKM0() asm volatile("s_waitcnt lgkmcnt(0)" ::: "memory")

// -------- dtype probe: fp32 (1) vs bf16 (0) from x's bit patterns --------
__global__ void k_probe(const void* __restrict__ x, int* __restrict__ flag) {
  if (threadIdx.x == 0 && blockIdx.x == 0) {
    const float* fb = (const float*)x;
    int okf = 0;
    for (int i = 0; i < 128; ++i) {
      const float av = fabsf(fb[i]);
      if (av > 1e-6f && av < 100.f) okf++;
    }
    *flag = (okf >= 115) ? 1 : 0;
  }
}

// ==================== phase 0: weight transposes + x conversion ============
// one 32x32 transpose tile; b<192: conv_w[i]; b<448: w1; else: w2
__device__ __forceinline__ void transpose_tile(
    char* smem_, const void* cw, const void* w1, const void* w2,
    ushort_t* cwT, ushort_t* w1T, ushort_t* w2T, int isf, int b, int tid) {
  ushort_t (*tile)[33] = (ushort_t(*)[33])smem_;
  const void* src; ushort_t* dst; int R, C, bx, by; size_t row0;
  if (b < 192) {
    const int i = b >> 6, t = b & 63;
    src = cw; dst = cwT + (size_t)i * DD * DD; row0 = (size_t)i * DD;
    R = DD; C = DD; bx = (t & 7) * 32; by = (t >> 3) * 32;
  } else if (b < 448) {
    const int t = b - 192;
    src = w1; dst = w1T; row0 = 0; R = DD; C = HH;
    bx = (t & 31) * 32; by = (t >> 5) * 32;
  } else {
    const int t = b - 448;
    src = w2; dst = w2T; row0 = 0; R = HH; C = DD;
    bx = (t & 7) * 32; by = (t >> 3) * 32;
  }
  const int tx = tid & 31, ty = tid >> 5;
  __syncthreads();
  for (int i = ty; i < 32; i += 8)
    tile[i][tx] = f2bf(ld_in(src, (row0 + by + i) * (size_t)C + bx + tx, isf));
  __syncthreads();
  for (int i = ty; i < 32; i += 8)
    dst[(size_t)(bx + i) * R + by + tx] = tile[tx][i];
}

// 512 blocks: blocks 0..191 do transpose tiles (bid, bid+512); 192..511 do
// tile bid.  All blocks convert their 1/512 slice of x.
__global__ __launch_bounds__(256) void k_phase0(
    const void* __restrict__ x, ushort_t* __restrict__ xA,
    const void* __restrict__ cw, const void* __restrict__ w1,
    const void* __restrict__ w2, ushort_t* __restrict__ cwT,
    ushort_t* __restrict__ w1T, ushort_t* __restrict__ w2T,
    const int* __restrict__ flag) {
  __shared__ alignas(16) char smem[4224];
  const int isf = *flag;
  const int bid = blockIdx.x, tid = threadIdx.x;
  transpose_tile(smem, cw, w1, w2, cwT, w1T, w2T, isf, bid, tid);
  if (bid < 192)
    transpose_tile(smem, cw, w1, w2, cwT, w1T, w2T, isf, 512 + bid, tid);
  // cvt: 8192 ushort4 per block (NR*DD/4 / 512)
  const size_t c0 = (size_t)bid * 8192 + tid;
  if (isf) {
    const float4* xf = (const float4*)x;
    ushort4* xo = (ushort4*)xA;
#pragma unroll
    for (int i = 0; i < 32; ++i) {
      const float4 f = xf[c0 + i * 256];
      ushort4 u; u.x = f2bf(f.x); u.y = f2bf(f.y); u.z = f2bf(f.z); u.w = f2bf(f.w);
      xo[c0 + i * 256] = u;
    }
  } else {
#pragma unroll
    for (int i = 0; i < 32; ++i)
      ((ushort4*)xA)[c0 + i * 256] = ((const ushort4*)x)[c0 + i * 256];
  }
}

// ==================== fused agg + conv layer (round-6 verified) ============
// 64 rows x 256 cols, 4 waves (64-col quarter each).  Swizzled LDS tiles;
// per-wave weight staging (vmcnt/lgkmcnt sync) -> K-loop has no block
// barriers.  Empirical local optimum: r8 (per-kc agg, 3/CU), r11 (nt-store,
// setprio), r12 (narrow slices, 3/CU) all regressed vs this body.
__global__ __launch_bounds__(256, 2) void k_conv_fused(
    const ushort_t* __restrict__ xin, ushort_t* __restrict__ xout,
    const ushort_t* __restrict__ Bt, const void* __restrict__ bias,
    size_t boff, const void* __restrict__ g, const void* __restrict__ bn,
    size_t goff, const int* __restrict__ flag) {
  __shared__ alignas(16) char smem[68096];
  float* scr    = (float*)smem;
  float* part   = scr;          // [4][64]
  float* partsq = scr + 256;    // [4][64]
  float* smu    = scr + 512;    // [64]
  float* srs    = scr + 576;    // [64]
  char* aggA    = smem + 2560;  // [4 kc][64][64] swizzled
  char* rt      = smem + 2560;  // [64][264] elems (epilogue alias)
  const int isf = *flag;

  const int tid  = threadIdx.x;
  const int lane = tid & 63;
  const int l16  = lane & 15;
  const int quad = lane >> 4;
  const int w    = tid >> 6;          // wave id = col quarter
  const int m0   = xcd_swz(blockIdx.x, gridDim.x) * 64;

  char* lB = smem + 35328 + w * 8192; // this wave's B slice [64][64] swizzled

  const int srow = lane >> 3;                   // 0..7
  const int sseg = (lane & 7) ^ (srow & 7);
  auto stageB = [&](int kc) {
#pragma unroll
    for (int i = 0; i < 8; ++i)
      gl_lds16(Bt + (size_t)(w * 64 + i * 8 + srow) * DD + kc * 64 + sseg * 8,
               lB + i * 1024);
  };
  stageB(0);   // in flight during the whole agg phase

  // ---- phase 1: aggregation into aggA (8 tasks/thread) ----
  const int tbase = m0 & (TT - 1);   // 64-row tile never crosses a batch
  const bool interior = (tbase >= 60) && (tbase <= TT - 124);
  const int koffs[8] = {-30, -15, -5, -1, 1, 5, 15, 30};
#pragma unroll
  for (int j = 0; j < 8; ++j) {
    const int id = j * 256 + tid;
    const int r = id >> 5, c = id & 31;
    const ushort_t* base = xin + (size_t)(m0 + r) * DD + c * 8;
    float s[8] = {0.f, 0.f, 0.f, 0.f, 0.f, 0.f, 0.f, 0.f};
    if (interior) {
#pragma unroll
      for (int e = 0; e < 8; ++e) {
        const short8 u = *(const short8*)(base + (ptrdiff_t)koffs[e] * DD);
#pragma unroll
        for (int q2 = 0; q2 < 8; ++q2) s[q2] += bf2f((ushort_t)u[q2]);
      }
#pragma unroll
      for (int q2 = 0; q2 < 8; ++q2) s[q2] *= 0.125f;
    } else {
      const int t = tbase + r;
      const float di = rsqrtf((float)deg_of(t));
#pragma unroll
      for (int e = 0; e < 8; ++e) {
        const int t2 = t + koffs[e];
        if ((unsigned)t2 < (unsigned)TT) {
          const float wgt = di * rsqrtf((float)deg_of(t2));
          const short8 u = *(const short8*)(base + (ptrdiff_t)koffs[e] * DD);
#pragma unroll
          for (int q2 = 0; q2 < 8; ++q2) s[q2] += wgt * bf2f((ushort_t)u[q2]);
        }
      }
    }
    short8 o;
#pragma unroll
    for (int q2 = 0; q2 < 8; ++q2) o[q2] = (short)f2bf(s[q2]);
    *(short8*)(aggA + (c >> 3) * 8192 + swz128(r, (c & 7) * 16)) = o;
  }
  WAIT_LGKM0();
  __builtin_amdgcn_s_barrier();      // aggA visible (raw: B stays in flight)
  __builtin_amdgcn_sched_barrier(0);

  // ---- phase 2: K-loop, barrier-free (per-wave staging sync) ----
  floatx4 acc[4][4];
#pragma unroll
  for (int i = 0; i < 4; ++i)
#pragma unroll
    for (int j = 0; j < 4; ++j) acc[i][j] = {0.f, 0.f, 0.f, 0.f};

#pragma unroll
  for (int kc = 0; kc < 4; ++kc) {
    WAIT_VM0();                      // this kc's B slice arrived
    short8 af0[4], bf0[4], af1[4], bf1[4];
#pragma unroll
    for (int mt = 0; mt < 4; ++mt) {
      af0[mt] = *(const short8*)(aggA + kc * 8192 +
                   swz128(mt * 16 + l16, quad * 16));
      af1[mt] = *(const short8*)(aggA + kc * 8192 +
                   swz128(mt * 16 + l16, 64 + quad * 16));
    }
#pragma unroll
    for (int nt = 0; nt < 4; ++nt) {
      bf0[nt] = *(const short8*)(lB + swz128(nt * 16 + l16, quad * 16));
      bf1[nt] = *(const short8*)(lB + swz128(nt * 16 + l16, 64 + quad * 16));
    }
    WAIT_LGKM0();                    // frag reads retired before overwrite
    __builtin_amdgcn_sched_barrier(0);
    if (kc < 3) stageB(kc + 1);      // prefetch hides under MFMAs below
#pragma unroll
    for (int mt = 0; mt < 4; ++mt)
#pragma unroll
      for (int nt = 0; nt < 4; ++nt)
        acc[mt][nt] = __builtin_amdgcn_mfma_f32_16x16x32_bf16(
            af0[mt], bf0[nt], acc[mt][nt], 0, 0, 0);
#pragma unroll
    for (int mt = 0; mt < 4; ++mt)
#pragma unroll
      for (int nt = 0; nt < 4; ++nt)
        acc[mt][nt] = __builtin_amdgcn_mfma_f32_16x16x32_bf16(
            af1[mt], bf1[nt], acc[mt][nt], 0, 0, 0);
  }

  // ---- phase 3: gelu+bias, block LN, residual ----
#pragma unroll
  for (int nt = 0; nt < 4; ++nt) {
    const float bv = ld_in(bias, boff + w * 64 + nt * 16 + l16, isf);
#pragma unroll
    for (int mt = 0; mt < 4; ++mt)
#pragma unroll
      for (int r = 0; r < 4; ++r)
        acc[mt][nt][r] = gelu_f(acc[mt][nt][r] + bv);
  }
#pragma unroll
  for (int mt = 0; mt < 4; ++mt) {
#pragma unroll
    for (int r = 0; r < 4; ++r) {
      float p = 0.f, q = 0.f;
#pragma unroll
      for (int nt = 0; nt < 4; ++nt) {
        const float v = acc[mt][nt][r];
        p += v; q += v * v;
      }
#pragma unroll
      for (int o = 8; o > 0; o >>= 1) {
        p += __shfl_xor(p, o, 64);
        q += __shfl_xor(q, o, 64);
      }
      if (l16 == 0) {
        const int rowloc = mt * 16 + quad * 4 + r;
        part[w * 64 + rowloc] = p;
        partsq[w * 64 + rowloc] = q;
      }
    }
  }
  __syncthreads();
  if (tid < 64) {
    const float s  = part[tid] + part[64 + tid] + part[128 + tid] + part[192 + tid];
    const float sq = partsq[tid] + partsq[64 + tid] + partsq[128 + tid] + partsq[192 + tid];
    const float mu = s * (1.0f / DD);
    const float var = sq * (1.0f / DD) - mu * mu;
    smu[tid] = mu;
    srs[tid] = rsqrtf(var + 1e-5f);
  }
  __syncthreads();

  // stage LN output into padded tile rt[64][264] (aliases aggA/lB, now dead)
#pragma unroll
  for (int nt = 0; nt < 4; ++nt) {
    const int col = w * 64 + nt * 16 + l16;
    const float gv = ld_in(g, goff + col, isf);
    const float bnv = ld_in(bn, goff + col, isf);
#pragma unroll
    for (int mt = 0; mt < 4; ++mt) {
#pragma unroll
      for (int r = 0; r < 4; ++r) {
        const int rowloc = mt * 16 + quad * 4 + r;
        *(ushort_t*)(rt + (rowloc * 264 + col) * 2) =
            f2bf((acc[mt][nt][r] - smu[rowloc]) * srs[rowloc] * gv + bnv);
      }
    }
  }
  __syncthreads();

  // coalesced: xout = xin + rt
#pragma unroll
  for (int i = 0; i < 8; ++i) {
    const int ch = tid + i * 256;        // 16B chunk id; 32 chunks/row
    const int row = ch >> 5, sg = ch & 31;
    const short8 xv = *(const short8*)(xin + (size_t)(m0 + row) * DD + sg * 8);
    const short8 rv = *(const short8*)(rt + (row * 264 + sg * 8) * 2);
    short8 ov;
#pragma unroll
    for (int j = 0; j < 8; ++j)
      ov[j] = (short)f2bf(bf2f((ushort_t)xv[j]) + bf2f((ushort_t)rv[j]));
    *(short8*)(xout + (size_t)(m0 + row) * DD + sg * 8) = ov;
  }
}

// ==================== fused FFN (counted-vmcnt pipeline, round-10) =========
// 64 rows/block, 256 thr (4 waves), 80KB LDS -> exactly 2 blocks/CU.
// All weight slices (8 per hidden chunk: 4 B1-kc + 4 B2-sub) form ONE
// 64-step per-wave pipeline, double-buffered (4KB x2 per wave):
//   step g: wait vmcnt(4)  [slice g landed; g+1 stays in flight]
//           frag-read buf[g&1]; lgkmcnt(0); issue slice g+2 into buf[g&1]
//           16 MFMAs.
// Only step 63 drains to vmcnt(0).  Pipeline flows across the 2 raw
// z-barriers per chunk (loads in flight; barriers don't drain vm).
__global__ __launch_bounds__(256, 2) void k_ffn(
    const ushort_t* __restrict__ xb, const ushort_t* __restrict__ w1T,
    const ushort_t* __restrict__ w2T, const void* __restrict__ gff,
    const void* __restrict__ bff, const void* __restrict__ b1,
    const void* __restrict__ b2, void* __restrict__ dout,
    const int* __restrict__ flag) {
  __shared__ alignas(16) char smem[81920];
  char* An = smem;            // [4 kc][64][64] LN(x), swizzled, 32KB
  char* Zs = smem + 32768;    // [2 kc2][64][64] z, swizzled, 16KB
  char* Rs = smem;            // resid [64][256] linear (aliases An, epilogue)
  const int isf = *flag;

  const int tid  = threadIdx.x;
  const int lane = tid & 63;
  const int l16  = lane & 15;
  const int quad = lane >> 4;
  const int w    = tid >> 6;      // 0..3
  const int m0   = xcd_swz(blockIdx.x, gridDim.x) * 64;
  char* Bw0 = smem + 49152 + w * 8192;   // this wave's dbuf: +0 / +4096

  const int sr8 = lane >> 3;                    // B1: [32][64] tile, 4 issues
  const int ss8 = (lane & 7) ^ (sr8 & 7);
  const int sr4 = lane >> 2;                    // B2: [64][32] tile, 4 issues
  const int ss4 = (lane & 3) ^ (sr4 & 3);

  // stage pipeline slice g (g = n1*8 + s; s<4: B1 kc=s, s>=4: B2 sub s-4)
  auto stage_g = [&](int gg) {
    if (gg >= 64) return;
    const int n1 = gg >> 3, s = gg & 7;
    char* dst = Bw0 + (gg & 1) * 4096;
    if (s < 4) {
#pragma unroll
      for (int i = 0; i < 4; ++i)
        gl_lds16(w1T + (size_t)(n1 * 128 + w * 32 + i * 8 + sr8) * DD +
                     s * 64 + ss8 * 8,
                 dst + i * 1024);
    } else {
      const int kc2 = (s - 4) >> 1, ks = (s - 4) & 1;
#pragma unroll
      for (int i = 0; i < 4; ++i)
        gl_lds16(w2T + (size_t)(w * 64 + i * 16 + sr4) * HH +
                     n1 * 128 + kc2 * 64 + ks * 32 + ss4 * 8,
                 dst + i * 1024);
    }
  };

  stage_g(0);      // slices 0,1 land during the LN prologue
  stage_g(1);

  // ---- LN prologue: 32-lane group per row, 8 passes ----
  const int sg = tid & 31;
  float gffv[8], bffv[8];
#pragma unroll
  for (int j = 0; j < 8; ++j) {
    gffv[j] = ld_in(gff, sg * 8 + j, isf);
    bffv[j] = ld_in(bff, sg * 8 + j, isf);
  }
#pragma unroll
  for (int i = 0; i < 8; ++i) {
    const int row = (tid + i * 256) >> 5;    // 0..63
    const short8 xv = *(const short8*)(xb + (size_t)(m0 + row) * DD + sg * 8);
    float v[8], ps = 0.f, pq = 0.f;
#pragma unroll
    for (int j = 0; j < 8; ++j) {
      v[j] = bf2f((ushort_t)xv[j]); ps += v[j]; pq += v[j] * v[j];
    }
#pragma unroll
    for (int o = 16; o > 0; o >>= 1) {
      ps += __shfl_xor(ps, o, 64);
      pq += __shfl_xor(pq, o, 64);
    }
    const float mu = ps * (1.0f / DD);
    const float rs = rsqrtf(pq * (1.0f / DD) - mu * mu + 1e-5f);
    short8 o8;
#pragma unroll
    for (int j = 0; j < 8; ++j)
      o8[j] = (short)f2bf((v[j] - mu) * rs * gffv[j] + bffv[j]);
    *(short8*)(An + (sg >> 3) * 8192 + swz128(row, (sg & 7) * 16)) = o8;
  }
  WAIT_LGKM0();
  __builtin_amdgcn_s_barrier();       // An visible (raw: slices in flight)
  __builtin_amdgcn_sched_barrier(0);

  floatx4 acc2[4][4];
#pragma unroll
  for (int i = 0; i < 4; ++i)
#pragma unroll
    for (int j = 0; j < 4; ++j) acc2[i][j] = {0.f, 0.f, 0.f, 0.f};

  for (int n1 = 0; n1 < 8; ++n1) {
    // b1 params for this chunk (issued early; retire in-order before slices)
    const float b1v0 = ld_in(b1, n1 * 128 + w * 32 + l16, isf);
    const float b1v1 = ld_in(b1, n1 * 128 + w * 32 + 16 + l16, isf);

    // ---- gemm1: z[64][128-chunk]; wave computes its 32 cols ----
    floatx4 acc1[4][2];
#pragma unroll
    for (int i = 0; i < 4; ++i)
#pragma unroll
      for (int j = 0; j < 2; ++j) acc1[i][j] = {0.f, 0.f, 0.f, 0.f};

#pragma unroll
    for (int kc = 0; kc < 4; ++kc) {
      const int gs = n1 * 8 + kc;
      WAIT_VM4();                      // slice gs landed; gs+1 in flight
      const char* Bw = Bw0 + (gs & 1) * 4096;
      short8 af0[4], af1[4], bq0[2], bq1[2];
#pragma unroll
      for (int mt = 0; mt < 4; ++mt) {
        af0[mt] = *(const short8*)(An + kc * 8192 +
                     swz128(mt * 16 + l16, quad * 16));
        af1[mt] = *(const short8*)(An + kc * 8192 +
                     swz128(mt * 16 + l16, 64 + quad * 16));
      }
#pragma unroll
      for (int nt = 0; nt < 2; ++nt) {
        bq0[nt] = *(const short8*)(Bw + swz128(nt * 16 + l16, quad * 16));
        bq1[nt] = *(const short8*)(Bw + swz128(nt * 16 + l16, 64 + quad * 16));
      }
      WAIT_LGKM0();                    // frag reads retired
      __builtin_amdgcn_sched_barrier(0);
      stage_g(gs + 2);                 // refill this buffer, 2 ahead
#pragma unroll
      for (int mt = 0; mt < 4; ++mt)
#pragma unroll
        for (int nt = 0; nt < 2; ++nt)
          acc1[mt][nt] = __builtin_amdgcn_mfma_f32_16x16x32_bf16(
              af0[mt], bq0[nt], acc1[mt][nt], 0, 0, 0);
#pragma unroll
      for (int mt = 0; mt < 4; ++mt)
#pragma unroll
        for (int nt = 0; nt < 2; ++nt)
          acc1[mt][nt] = __builtin_amdgcn_mfma_f32_16x16x32_bf16(
              af1[mt], bq1[nt], acc1[mt][nt], 0, 0, 0);
    }

    // ---- gelu + b1 -> z (swizzled scalar writes) ----
#pragma unroll
    for (int nt = 0; nt < 2; ++nt) {
      const int col = w * 32 + nt * 16 + l16;           // 0..127 in chunk
      const float b1v = nt ? b1v1 : b1v0;
#pragma unroll
      for (int mt = 0; mt < 4; ++mt)
#pragma unroll
        for (int r = 0; r < 4; ++r) {
          const int row = mt * 16 + quad * 4 + r;
          *(ushort_t*)(Zs + (col >> 6) * 8192 + swz128(row, (col & 63) * 2)) =
              f2bf(gelu_f(acc1[mt][nt][r] + b1v));
        }
    }
    WAIT_LGKM0();
    __builtin_amdgcn_s_barrier();      // z visible (raw: slices in flight)
    __builtin_amdgcn_sched_barrier(0);

    // ---- gemm2 partial: acc2 += z @ W2-slice ----
#pragma unroll
    for (int s2 = 0; s2 < 4; ++s2) {
      const int gs = n1 * 8 + 4 + s2;
      const int kc2 = s2 >> 1, ks = s2 & 1;
      if (gs == 63) { WAIT_VM0(); } else { WAIT_VM4(); }
      const char* Bw = Bw0 + (gs & 1) * 4096;
      short8 af[4], bfr[4];
#pragma unroll
      for (int mt = 0; mt < 4; ++mt)
        af[mt] = *(const short8*)(Zs + kc2 * 8192 +
                   swz128(mt * 16 + l16, ks * 64 + quad * 16));
#pragma unroll
      for (int nt = 0; nt < 4; ++nt)
        bfr[nt] = *(const short8*)(Bw + swz64(nt * 16 + l16, quad * 16));
      WAIT_LGKM0();
      __builtin_amdgcn_sched_barrier(0);
      stage_g(gs + 2);
#pragma unroll
      for (int mt = 0; mt < 4; ++mt)
#pragma unroll
        for (int nt = 0; nt < 4; ++nt)
          acc2[mt][nt] = __builtin_amdgcn_mfma_f32_16x16x32_bf16(
              af[mt], bfr[nt], acc2[mt][nt], 0, 0, 0);
    }
    __builtin_amdgcn_s_barrier();      // z consumed; next n1 may overwrite
    __builtin_amdgcn_sched_barrier(0);
  }

  // ---- epilogue: stage resid into Rs (An dead), add b2, store ----
  WAIT_VM0();                          // pipeline fully drained
#pragma unroll
  for (int i = 0; i < 8; ++i)          // [64][256] bf16 = 32KB, linear
    gl_lds16(xb + (size_t)(m0 + ((i * 256 + tid) >> 5)) * DD +
                 ((i * 256 + tid) & 31) * 8,
             Rs + i * 4096 + w * 1024);
  __syncthreads();                     // full drain + barrier

#pragma unroll
  for (int nt = 0; nt < 4; ++nt) {
    const int col = w * 64 + nt * 16 + l16;
    const float b2v = ld_in(b2, col, isf);
#pragma unroll
    for (int mt = 0; mt < 4; ++mt) {
#pragma unroll
      for (int r = 0; r < 4; ++r) {
        const int lr = mt * 16 + quad * 4 + r;
        const float v = acc2[mt][nt][r] + b2v +
                        bf2f(*(const ushort_t*)(Rs + lr * 512 + col * 2));
        const size_t idx = (size_t)(m0 + lr) * DD + col;
        if (isf) ((float*)dout)[idx] = v;
        else     ((ushort_t*)dout)[idx] = f2bf(v);
      }
    }
  }
}

extern "C" void kernel_launch(void* const* d_in, const int* in_sizes, int n_in,
                              void* d_out, int out_size, void* d_ws, size_t ws_size,
                              hipStream_t stream) {
  const void* x      = d_in[0];
  const void* conv_w = d_in[3];
  const void* conv_b = d_in[4];
  const void* norm_g = d_in[5];
  const void* norm_b = d_in[6];
  const void* nff_g  = d_in[7];
  const void* nff_b  = d_in[8];
  const void* w1     = d_in[9];
  const void* b1     = d_in[10];
  const void* w2     = d_in[11];
  const void* b2     = d_in[12];
  (void)in_sizes; (void)n_in; (void)out_size; (void)ws_size;

  char* ws = (char*)d_ws;
  int*      flag = (int*)ws;      ws += 16;
  ushort_t* xA   = (ushort_t*)ws; ws += (size_t)NR * DD * 2;
  ushort_t* xB   = (ushort_t*)ws; ws += (size_t)NR * DD * 2;
  ushort_t* cwT  = (ushort_t*)ws; ws += (size_t)LL * DD * DD * 2;
  ushort_t* w1T  = (ushort_t*)ws; ws += (size_t)DD * HH * 2;
  ushort_t* w2T  = (ushort_t*)ws; ws += (size_t)HH * DD * 2;

  k_probe<<<1, 64, 0, stream>>>(x, flag);
  k_phase0<<<512, 256, 0, stream>>>(x, xA, conv_w, w1, w2, cwT, w1T, w2T,
                                    flag);

  // conv layers ping-pong xA <-> xB; final state lands in xB
  k_conv_fused<<<NR / 64, 256, 0, stream>>>(
      xA, xB, cwT, conv_b, 0, norm_g, norm_b, 0, flag);
  k_conv_fused<<<NR / 64, 256, 0, stream>>>(
      xB, xA, cwT + (size_t)DD * DD, conv_b, DD, norm_g, norm_b, DD, flag);
  k_conv_fused<<<NR / 64, 256, 0, stream>>>(
      xA, xB, cwT + (size_t)2 * DD * DD, conv_b, 2 * DD, norm_g, norm_b,
      2 * DD, flag);

  // fused FFN: LN + GEMM1 + GELU + GEMM2 + residual, one launch
  k_ffn<<<NR / 64, 256, 0, stream>>>(
      xB, w1T, w2T, nff_g, nff_b, b1, b2, d_out, flag);
}

// Round 14
// 614.909 us; speedup vs baseline: 1.0678x; 1.0182x over previous
//
#include <hip/hip_runtime.h>
#include <hip/hip_bf16.h>
#include <math.h>
#include <stdint.h>
#include <stddef.h>

// Problem constants (fixed by the reference)
#define TB 8
#define TT 8192
#define DD 256
#define NR (TB * TT)   // 65536 rows
#define HH 1024        // 4*D
#define LL 3

typedef unsigned short ushort_t;
typedef __attribute__((ext_vector_type(8))) short short8;   // 8 bf16 in 4 VGPRs
typedef __attribute__((ext_vector_type(4))) float floatx4;  // MFMA accumulator

__device__ __forceinline__ float bf2f(ushort_t u) {
  union { unsigned int i; float f; } x; x.i = ((unsigned int)u) << 16; return x.f;
}
__device__ __forceinline__ ushort_t f2bf(float f) {
  union { float f; unsigned int i; } x; x.f = f;
  unsigned int r = x.i + 0x7fffu + ((x.i >> 16) & 1u);  // RNE
  return (ushort_t)(r >> 16);
}
__device__ __forceinline__ float ld_in(const void* p, size_t i, int isf) {
  return isf ? ((const float*)p)[i] : bf2f(((const ushort_t*)p)[i]);
}
// tanh-form GELU via hardware exp (~8 VALU insts; |err| vs erf-gelu ~3e-4)
__device__ __forceinline__ float gelu_f(float v) {
  const float y = v * (0.7978845608028654f + 0.035677408136300125f * v * v);
  const float e = __expf(-2.0f * y);
  return v * __builtin_amdgcn_rcpf(1.0f + e);
}
__device__ __forceinline__ int deg_of(int t) {
  return (t >= 1) + (t >= 5) + (t >= 15) + (t >= 30)
       + (t < TT - 1) + (t < TT - 5) + (t < TT - 15) + (t < TT - 30);
}
// async global->LDS, 16B per lane; lds ptr must be wave-uniform base
__device__ __forceinline__ void gl_lds16(const ushort_t* g, void* l) {
  __builtin_amdgcn_global_load_lds(
      (const __attribute__((address_space(1))) unsigned int*)(g),
      (__attribute__((address_space(3))) unsigned int*)(l), 16, 0, 0);
}
// bijective XCD swizzle (m204 form; requires nwg % 8 == 0)
__device__ __forceinline__ int xcd_swz(int lin, int nwg) {
  const int q = nwg >> 3;
  return (lin & 7) * q + (lin >> 3);
}
// T2 XOR swizzles: permute 16B chunks within a row (bijective per row)
__device__ __forceinline__ int swz128(int row, int bytecol) {
  return row * 128 + (bytecol ^ ((row & 7) << 4));
}
__device__ __forceinline__ int swz64(int row, int bytecol) {
  return row * 64 + (bytecol ^ ((row & 3) << 4));
}
#define WAIT_VM0()  asm volatile("s_waitcnt vmcnt(0)" ::: "memory")
#define WAIT_VM4()  asm volatile("s_waitcnt vmcnt(4)" ::: "memory")
#define WAIT_LGKM0() asm volatile("s_waitcnt lgkmcnt(0)" ::: "memory")

// -------- inline dtype probe: fp32 (1) vs bf16 (0) from x's bit patterns ---
// All 64 lanes read 2 floats of x[0..127] (512B, L1-broadcast), 6-step
// shuffle reduce; identical threshold to the old k_probe.  Wave-uniform ->
// block-uniform.  Replaces the serial 1-thread k_probe launch.
__device__ __forceinline__ int probe_isf(const void* x) {
  const int lane = threadIdx.x & 63;
  const float* fb = (const float*)x;
  int ok = 0;
#pragma unroll
  for (int i = 0; i < 2; ++i) {
    const float av = fabsf(fb[lane * 2 + i]);
    ok += (av > 1e-6f && av < 100.f) ? 1 : 0;
  }
#pragma unroll
  for (int o = 32; o > 0; o >>= 1) ok += __shfl_xor(ok, o, 64);
  return ok >= 115;
}

// ==================== phase 0: weight transposes + x conversion ============
// one 32x32 transpose tile; b<192: conv_w[i]; b<448: w1; else: w2
__device__ __forceinline__ void transpose_tile(
    char* smem_, const void* cw, const void* w1, const void* w2,
    ushort_t* cwT, ushort_t* w1T, ushort_t* w2T, int isf, int b, int tid) {
  ushort_t (*tile)[33] = (ushort_t(*)[33])smem_;
  const void* src; ushort_t* dst; int R, C, bx, by; size_t row0;
  if (b < 192) {
    const int i = b >> 6, t = b & 63;
    src = cw; dst = cwT + (size_t)i * DD * DD; row0 = (size_t)i * DD;
    R = DD; C = DD; bx = (t & 7) * 32; by = (t >> 3) * 32;
  } else if (b < 448) {
    const int t = b - 192;
    src = w1; dst = w1T; row0 = 0; R = DD; C = HH;
    bx = (t & 31) * 32; by = (t >> 5) * 32;
  } else {
    const int t = b - 448;
    src = w2; dst = w2T; row0 = 0; R = HH; C = DD;
    bx = (t & 7) * 32; by = (t >> 3) * 32;
  }
  const int tx = tid & 31, ty = tid >> 5;
  __syncthreads();
  for (int i = ty; i < 32; i += 8)
    tile[i][tx] = f2bf(ld_in(src, (row0 + by + i) * (size_t)C + bx + tx, isf));
  __syncthreads();
  for (int i = ty; i < 32; i += 8)
    dst[(size_t)(bx + i) * R + by + tx] = tile[tx][i];
}

// 512 blocks: blocks 0..191 do transpose tiles (bid, bid+512); 192..511 do
// tile bid.  All blocks convert their 1/512 slice of x.
__global__ __launch_bounds__(256) void k_phase0(
    const void* __restrict__ x, ushort_t* __restrict__ xA,
    const void* __restrict__ cw, const void* __restrict__ w1,
    const void* __restrict__ w2, ushort_t* __restrict__ cwT,
    ushort_t* __restrict__ w1T, ushort_t* __restrict__ w2T) {
  __shared__ alignas(16) char smem[4224];
  const int isf = probe_isf(x);
  const int bid = blockIdx.x, tid = threadIdx.x;
  transpose_tile(smem, cw, w1, w2, cwT, w1T, w2T, isf, bid, tid);
  if (bid < 192)
    transpose_tile(smem, cw, w1, w2, cwT, w1T, w2T, isf, 512 + bid, tid);
  // cvt: 8192 ushort4 per block (NR*DD/4 / 512)
  const size_t c0 = (size_t)bid * 8192 + tid;
  if (isf) {
    const float4* xf = (const float4*)x;
    ushort4* xo = (ushort4*)xA;
#pragma unroll
    for (int i = 0; i < 32; ++i) {
      const float4 f = xf[c0 + i * 256];
      ushort4 u; u.x = f2bf(f.x); u.y = f2bf(f.y); u.z = f2bf(f.z); u.w = f2bf(f.w);
      xo[c0 + i * 256] = u;
    }
  } else {
#pragma unroll
    for (int i = 0; i < 32; ++i)
      ((ushort4*)xA)[c0 + i * 256] = ((const ushort4*)x)[c0 + i * 256];
  }
}

// ==================== fused agg + conv layer (round-6 verified) ============
// 64 rows x 256 cols, 4 waves (64-col quarter each).  Swizzled LDS tiles;
// per-wave weight staging (vmcnt/lgkmcnt sync) -> K-loop has no block
// barriers.  Empirical local optimum: r8 (per-kc agg, 3/CU), r11 (nt-store,
// setprio), r12 (narrow slices, 3/CU) all regressed vs this body.
__global__ __launch_bounds__(256, 2) void k_conv_fused(
    const void* __restrict__ xorig, const ushort_t* __restrict__ xin,
    ushort_t* __restrict__ xout, const ushort_t* __restrict__ Bt,
    const void* __restrict__ bias, size_t boff, const void* __restrict__ g,
    const void* __restrict__ bn, size_t goff) {
  __shared__ alignas(16) char smem[68096];
  float* scr    = (float*)smem;
  float* part   = scr;          // [4][64]
  float* partsq = scr + 256;    // [4][64]
  float* smu    = scr + 512;    // [64]
  float* srs    = scr + 576;    // [64]
  char* aggA    = smem + 2560;  // [4 kc][64][64] swizzled
  char* rt      = smem + 2560;  // [64][264] elems (epilogue alias)
  const int isf = probe_isf(xorig);

  const int tid  = threadIdx.x;
  const int lane = tid & 63;
  const int l16  = lane & 15;
  const int quad = lane >> 4;
  const int w    = tid >> 6;          // wave id = col quarter
  const int m0   = xcd_swz(blockIdx.x, gridDim.x) * 64;

  char* lB = smem + 35328 + w * 8192; // this wave's B slice [64][64] swizzled

  const int srow = lane >> 3;                   // 0..7
  const int sseg = (lane & 7) ^ (srow & 7);
  auto stageB = [&](int kc) {
#pragma unroll
    for (int i = 0; i < 8; ++i)
      gl_lds16(Bt + (size_t)(w * 64 + i * 8 + srow) * DD + kc * 64 + sseg * 8,
               lB + i * 1024);
  };
  stageB(0);   // in flight during the whole agg phase

  // ---- phase 1: aggregation into aggA (8 tasks/thread) ----
  const int tbase = m0 & (TT - 1);   // 64-row tile never crosses a batch
  const bool interior = (tbase >= 60) && (tbase <= TT - 124);
  const int koffs[8] = {-30, -15, -5, -1, 1, 5, 15, 30};
#pragma unroll
  for (int j = 0; j < 8; ++j) {
    const int id = j * 256 + tid;
    const int r = id >> 5, c = id & 31;
    const ushort_t* base = xin + (size_t)(m0 + r) * DD + c * 8;
    float s[8] = {0.f, 0.f, 0.f, 0.f, 0.f, 0.f, 0.f, 0.f};
    if (interior) {
#pragma unroll
      for (int e = 0; e < 8; ++e) {
        const short8 u = *(const short8*)(base + (ptrdiff_t)koffs[e] * DD);
#pragma unroll
        for (int q2 = 0; q2 < 8; ++q2) s[q2] += bf2f((ushort_t)u[q2]);
      }
#pragma unroll
      for (int q2 = 0; q2 < 8; ++q2) s[q2] *= 0.125f;
    } else {
      const int t = tbase + r;
      const float di = rsqrtf((float)deg_of(t));
#pragma unroll
      for (int e = 0; e < 8; ++e) {
        const int t2 = t + koffs[e];
        if ((unsigned)t2 < (unsigned)TT) {
          const float wgt = di * rsqrtf((float)deg_of(t2));
          const short8 u = *(const short8*)(base + (ptrdiff_t)koffs[e] * DD);
#pragma unroll
          for (int q2 = 0; q2 < 8; ++q2) s[q2] += wgt * bf2f((ushort_t)u[q2]);
        }
      }
    }
    short8 o;
#pragma unroll
    for (int q2 = 0; q2 < 8; ++q2) o[q2] = (short)f2bf(s[q2]);
    *(short8*)(aggA + (c >> 3) * 8192 + swz128(r, (c & 7) * 16)) = o;
  }
  WAIT_LGKM0();
  __builtin_amdgcn_s_barrier();      // aggA visible (raw: B stays in flight)
  __builtin_amdgcn_sched_barrier(0);

  // ---- phase 2: K-loop, barrier-free (per-wave staging sync) ----
  floatx4 acc[4][4];
#pragma unroll
  for (int i = 0; i < 4; ++i)
#pragma unroll
    for (int j = 0; j < 4; ++j) acc[i][j] = {0.f, 0.f, 0.f, 0.f};

#pragma unroll
  for (int kc = 0; kc < 4; ++kc) {
    WAIT_VM0();                      // this kc's B slice arrived
    short8 af0[4], bf0[4], af1[4], bf1[4];
#pragma unroll
    for (int mt = 0; mt < 4; ++mt) {
      af0[mt] = *(const short8*)(aggA + kc * 8192 +
                   swz128(mt * 16 + l16, quad * 16));
      af1[mt] = *(const short8*)(aggA + kc * 8192 +
                   swz128(mt * 16 + l16, 64 + quad * 16));
    }
#pragma unroll
    for (int nt = 0; nt < 4; ++nt) {
      bf0[nt] = *(const short8*)(lB + swz128(nt * 16 + l16, quad * 16));
      bf1[nt] = *(const short8*)(lB + swz128(nt * 16 + l16, 64 + quad * 16));
    }
    WAIT_LGKM0();                    // frag reads retired before overwrite
    __builtin_amdgcn_sched_barrier(0);
    if (kc < 3) stageB(kc + 1);      // prefetch hides under MFMAs below
#pragma unroll
    for (int mt = 0; mt < 4; ++mt)
#pragma unroll
      for (int nt = 0; nt < 4; ++nt)
        acc[mt][nt] = __builtin_amdgcn_mfma_f32_16x16x32_bf16(
            af0[mt], bf0[nt], acc[mt][nt], 0, 0, 0);
#pragma unroll
    for (int mt = 0; mt < 4; ++mt)
#pragma unroll
      for (int nt = 0; nt < 4; ++nt)
        acc[mt][nt] = __builtin_amdgcn_mfma_f32_16x16x32_bf16(
            af1[mt], bf1[nt], acc[mt][nt], 0, 0, 0);
  }

  // ---- phase 3: gelu+bias, block LN, residual ----
#pragma unroll
  for (int nt = 0; nt < 4; ++nt) {
    const float bv = ld_in(bias, boff + w * 64 + nt * 16 + l16, isf);
#pragma unroll
    for (int mt = 0; mt < 4; ++mt)
#pragma unroll
      for (int r = 0; r < 4; ++r)
        acc[mt][nt][r] = gelu_f(acc[mt][nt][r] + bv);
  }
#pragma unroll
  for (int mt = 0; mt < 4; ++mt) {
#pragma unroll
    for (int r = 0; r < 4; ++r) {
      float p = 0.f, q = 0.f;
#pragma unroll
      for (int nt = 0; nt < 4; ++nt) {
        const float v = acc[mt][nt][r];
        p += v; q += v * v;
      }
#pragma unroll
      for (int o = 8; o > 0; o >>= 1) {
        p += __shfl_xor(p, o, 64);
        q += __shfl_xor(q, o, 64);
      }
      if (l16 == 0) {
        const int rowloc = mt * 16 + quad * 4 + r;
        part[w * 64 + rowloc] = p;
        partsq[w * 64 + rowloc] = q;
      }
    }
  }
  __syncthreads();
  if (tid < 64) {
    const float s  = part[tid] + part[64 + tid] + part[128 + tid] + part[192 + tid];
    const float sq = partsq[tid] + partsq[64 + tid] + partsq[128 + tid] + partsq[192 + tid];
    const float mu = s * (1.0f / DD);
    const float var = sq * (1.0f / DD) - mu * mu;
    smu[tid] = mu;
    srs[tid] = rsqrtf(var + 1e-5f);
  }
  __syncthreads();

  // stage LN output into padded tile rt[64][264] (aliases aggA/lB, now dead)
#pragma unroll
  for (int nt = 0; nt < 4; ++nt) {
    const int col = w * 64 + nt * 16 + l16;
    const float gv = ld_in(g, goff + col, isf);
    const float bnv = ld_in(bn, goff + col, isf);
#pragma unroll
    for (int mt = 0; mt < 4; ++mt) {
#pragma unroll
      for (int r = 0; r < 4; ++r) {
        const int rowloc = mt * 16 + quad * 4 + r;
        *(ushort_t*)(rt + (rowloc * 264 + col) * 2) =
            f2bf((acc[mt][nt][r] - smu[rowloc]) * srs[rowloc] * gv + bnv);
      }
    }
  }
  __syncthreads();

  // coalesced: xout = xin + rt
#pragma unroll
  for (int i = 0; i < 8; ++i) {
    const int ch = tid + i * 256;        // 16B chunk id; 32 chunks/row
    const int row = ch >> 5, sg = ch & 31;
    const short8 xv = *(const short8*)(xin + (size_t)(m0 + row) * DD + sg * 8);
    const short8 rv = *(const short8*)(rt + (row * 264 + sg * 8) * 2);
    short8 ov;
#pragma unroll
    for (int j = 0; j < 8; ++j)
      ov[j] = (short)f2bf(bf2f((ushort_t)xv[j]) + bf2f((ushort_t)rv[j]));
    *(short8*)(xout + (size_t)(m0 + row) * DD + sg * 8) = ov;
  }
}

// ==================== fused FFN (counted-vmcnt pipeline, round-10) =========
// 64 rows/block, 256 thr (4 waves), 80KB LDS -> exactly 2 blocks/CU.
// All weight slices (8 per hidden chunk: 4 B1-kc + 4 B2-sub) form ONE
// 64-step per-wave pipeline, double-buffered (4KB x2 per wave):
//   step g: wait vmcnt(4)  [slice g landed; g+1 stays in flight]
//           frag-read buf[g&1]; lgkmcnt(0); issue slice g+2 into buf[g&1]
//           16 MFMAs.
// Only step 63 drains to vmcnt(0).  Pipeline flows across the 2 raw
// z-barriers per chunk (loads in flight; barriers don't drain vm).
__global__ __launch_bounds__(256, 2) void k_ffn(
    const void* __restrict__ xorig, const ushort_t* __restrict__ xb,
    const ushort_t* __restrict__ w1T, const ushort_t* __restrict__ w2T,
    const void* __restrict__ gff, const void* __restrict__ bff,
    const void* __restrict__ b1, const void* __restrict__ b2,
    void* __restrict__ dout) {
  __shared__ alignas(16) char smem[81920];
  char* An = smem;            // [4 kc][64][64] LN(x), swizzled, 32KB
  char* Zs = smem + 32768;    // [2 kc2][64][64] z, swizzled, 16KB
  char* Rs = smem;            // resid [64][256] linear (aliases An, epilogue)
  const int isf = probe_isf(xorig);

  const int tid  = threadIdx.x;
  const int lane = tid & 63;
  const int l16  = lane & 15;
  const int quad = lane >> 4;
  const int w    = tid >> 6;      // 0..3
  const int m0   = xcd_swz(blockIdx.x, gridDim.x) * 64;
  char* Bw0 = smem + 49152 + w * 8192;   // this wave's dbuf: +0 / +4096

  const int sr8 = lane >> 3;                    // B1: [32][64] tile, 4 issues
  const int ss8 = (lane & 7) ^ (sr8 & 7);
  const int sr4 = lane >> 2;                    // B2: [64][32] tile, 4 issues
  const int ss4 = (lane & 3) ^ (sr4 & 3);

  // stage pipeline slice g (g = n1*8 + s; s<4: B1 kc=s, s>=4: B2 sub s-4)
  auto stage_g = [&](int gg) {
    if (gg >= 64) return;
    const int n1 = gg >> 3, s = gg & 7;
    char* dst = Bw0 + (gg & 1) * 4096;
    if (s < 4) {
#pragma unroll
      for (int i = 0; i < 4; ++i)
        gl_lds16(w1T + (size_t)(n1 * 128 + w * 32 + i * 8 + sr8) * DD +
                     s * 64 + ss8 * 8,
                 dst + i * 1024);
    } else {
      const int kc2 = (s - 4) >> 1, ks = (s - 4) & 1;
#pragma unroll
      for (int i = 0; i < 4; ++i)
        gl_lds16(w2T + (size_t)(w * 64 + i * 16 + sr4) * HH +
                     n1 * 128 + kc2 * 64 + ks * 32 + ss4 * 8,
                 dst + i * 1024);
    }
  };

  stage_g(0);      // slices 0,1 land during the LN prologue
  stage_g(1);

  // ---- LN prologue: 32-lane group per row, 8 passes ----
  const int sg = tid & 31;
  float gffv[8], bffv[8];
#pragma unroll
  for (int j = 0; j < 8; ++j) {
    gffv[j] = ld_in(gff, sg * 8 + j, isf);
    bffv[j] = ld_in(bff, sg * 8 + j, isf);
  }
#pragma unroll
  for (int i = 0; i < 8; ++i) {
    const int row = (tid + i * 256) >> 5;    // 0..63
    const short8 xv = *(const short8*)(xb + (size_t)(m0 + row) * DD + sg * 8);
    float v[8], ps = 0.f, pq = 0.f;
#pragma unroll
    for (int j = 0; j < 8; ++j) {
      v[j] = bf2f((ushort_t)xv[j]); ps += v[j]; pq += v[j] * v[j];
    }
#pragma unroll
    for (int o = 16; o > 0; o >>= 1) {
      ps += __shfl_xor(ps, o, 64);
      pq += __shfl_xor(pq, o, 64);
    }
    const float mu = ps * (1.0f / DD);
    const float rs = rsqrtf(pq * (1.0f / DD) - mu * mu + 1e-5f);
    short8 o8;
#pragma unroll
    for (int j = 0; j < 8; ++j)
      o8[j] = (short)f2bf((v[j] - mu) * rs * gffv[j] + bffv[j]);
    *(short8*)(An + (sg >> 3) * 8192 + swz128(row, (sg & 7) * 16)) = o8;
  }
  WAIT_LGKM0();
  __builtin_amdgcn_s_barrier();       // An visible (raw: slices in flight)
  __builtin_amdgcn_sched_barrier(0);

  floatx4 acc2[4][4];
#pragma unroll
  for (int i = 0; i < 4; ++i)
#pragma unroll
    for (int j = 0; j < 4; ++j) acc2[i][j] = {0.f, 0.f, 0.f, 0.f};

  for (int n1 = 0; n1 < 8; ++n1) {
    // b1 params for this chunk (issued early; retire in-order before slices)
    const float b1v0 = ld_in(b1, n1 * 128 + w * 32 + l16, isf);
    const float b1v1 = ld_in(b1, n1 * 128 + w * 32 + 16 + l16, isf);

    // ---- gemm1: z[64][128-chunk]; wave computes its 32 cols ----
    floatx4 acc1[4][2];
#pragma unroll
    for (int i = 0; i < 4; ++i)
#pragma unroll
      for (int j = 0; j < 2; ++j) acc1[i][j] = {0.f, 0.f, 0.f, 0.f};

#pragma unroll
    for (int kc = 0; kc < 4; ++kc) {
      const int gs = n1 * 8 + kc;
      WAIT_VM4();                      // slice gs landed; gs+1 in flight
      const char* Bw = Bw0 + (gs & 1) * 4096;
      short8 af0[4], af1[4], bq0[2], bq1[2];
#pragma unroll
      for (int mt = 0; mt < 4; ++mt) {
        af0[mt] = *(const short8*)(An + kc * 8192 +
                     swz128(mt * 16 + l16, quad * 16));
        af1[mt] = *(const short8*)(An + kc * 8192 +
                     swz128(mt * 16 + l16, 64 + quad * 16));
      }
#pragma unroll
      for (int nt = 0; nt < 2; ++nt) {
        bq0[nt] = *(const short8*)(Bw + swz128(nt * 16 + l16, quad * 16));
        bq1[nt] = *(const short8*)(Bw + swz128(nt * 16 + l16, 64 + quad * 16));
      }
      WAIT_LGKM0();                    // frag reads retired
      __builtin_amdgcn_sched_barrier(0);
      stage_g(gs + 2);                 // refill this buffer, 2 ahead
#pragma unroll
      for (int mt = 0; mt < 4; ++mt)
#pragma unroll
        for (int nt = 0; nt < 2; ++nt)
          acc1[mt][nt] = __builtin_amdgcn_mfma_f32_16x16x32_bf16(
              af0[mt], bq0[nt], acc1[mt][nt], 0, 0, 0);
#pragma unroll
      for (int mt = 0; mt < 4; ++mt)
#pragma unroll
        for (int nt = 0; nt < 2; ++nt)
          acc1[mt][nt] = __builtin_amdgcn_mfma_f32_16x16x32_bf16(
              af1[mt], bq1[nt], acc1[mt][nt], 0, 0, 0);
    }

    // ---- gelu + b1 -> z (swizzled scalar writes) ----
#pragma unroll
    for (int nt = 0; nt < 2; ++nt) {
      const int col = w * 32 + nt * 16 + l16;           // 0..127 in chunk
      const float b1v = nt ? b1v1 : b1v0;
#pragma unroll
      for (int mt = 0; mt < 4; ++mt)
#pragma unroll
        for (int r = 0; r < 4; ++r) {
          const int row = mt * 16 + quad * 4 + r;
          *(ushort_t*)(Zs + (col >> 6) * 8192 + swz128(row, (col & 63) * 2)) =
              f2bf(gelu_f(acc1[mt][nt][r] + b1v));
        }
    }
    WAIT_LGKM0();
    __builtin_amdgcn_s_barrier();      // z visible (raw: slices in flight)
    __builtin_amdgcn_sched_barrier(0);

    // ---- gemm2 partial: acc2 += z @ W2-slice ----
#pragma unroll
    for (int s2 = 0; s2 < 4; ++s2) {
      const int gs = n1 * 8 + 4 + s2;
      const int kc2 = s2 >> 1, ks = s2 & 1;
      if (gs == 63) { WAIT_VM0(); } else { WAIT_VM4(); }
      const char* Bw = Bw0 + (gs & 1) * 4096;
      short8 af[4], bfr[4];
#pragma unroll
      for (int mt = 0; mt < 4; ++mt)
        af[mt] = *(const short8*)(Zs + kc2 * 8192 +
                   swz128(mt * 16 + l16, ks * 64 + quad * 16));
#pragma unroll
      for (int nt = 0; nt < 4; ++nt)
        bfr[nt] = *(const short8*)(Bw + swz64(nt * 16 + l16, quad * 16));
      WAIT_LGKM0();
      __builtin_amdgcn_sched_barrier(0);
      stage_g(gs + 2);
#pragma unroll
      for (int mt = 0; mt < 4; ++mt)
#pragma unroll
        for (int nt = 0; nt < 4; ++nt)
          acc2[mt][nt] = __builtin_amdgcn_mfma_f32_16x16x32_bf16(
              af[mt], bfr[nt], acc2[mt][nt], 0, 0, 0);
    }
    __builtin_amdgcn_s_barrier();      // z consumed; next n1 may overwrite
    __builtin_amdgcn_sched_barrier(0);
  }

  // ---- epilogue: stage resid into Rs (An dead), add b2, store ----
  WAIT_VM0();                          // pipeline fully drained
#pragma unroll
  for (int i = 0; i < 8; ++i)          // [64][256] bf16 = 32KB, linear
    gl_lds16(xb + (size_t)(m0 + ((i * 256 + tid) >> 5)) * DD +
                 ((i * 256 + tid) & 31) * 8,
             Rs + i * 4096 + w * 1024);
  __syncthreads();                     // full drain + barrier

#pragma unroll
  for (int nt = 0; nt < 4; ++nt) {
    const int col = w * 64 + nt * 16 + l16;
    const float b2v = ld_in(b2, col, isf);
#pragma unroll
    for (int mt = 0; mt < 4; ++mt) {
#pragma unroll
      for (int r = 0; r < 4; ++r) {
        const int lr = mt * 16 + quad * 4 + r;
        const float v = acc2[mt][nt][r] + b2v +
                        bf2f(*(const ushort_t*)(Rs + lr * 512 + col * 2));
        const size_t idx = (size_t)(m0 + lr) * DD + col;
        if (isf) ((float*)dout)[idx] = v;
        else     ((ushort_t*)dout)[idx] = f2bf(v);
      }
    }
  }
}

extern "C" void kernel_launch(void* const* d_in, const int* in_sizes, int n_in,
                              void* d_out, int out_size, void* d_ws, size_t ws_size,
                              hipStream_t stream) {
  const void* x      = d_in[0];
  const void* conv_w = d_in[3];
  const void* conv_b = d_in[4];
  const void* norm_g = d_in[5];
  const void* norm_b = d_in[6];
  const void* nff_g  = d_in[7];
  const void* nff_b  = d_in[8];
  const void* w1     = d_in[9];
  const void* b1     = d_in[10];
  const void* w2     = d_in[11];
  const void* b2     = d_in[12];
  (void)in_sizes; (void)n_in; (void)out_size; (void)ws_size;

  char* ws = (char*)d_ws;
  ushort_t* xA   = (ushort_t*)ws; ws += (size_t)NR * DD * 2;
  ushort_t* xB   = (ushort_t*)ws; ws += (size_t)NR * DD * 2;
  ushort_t* cwT  = (ushort_t*)ws; ws += (size_t)LL * DD * DD * 2;
  ushort_t* w1T  = (ushort_t*)ws; ws += (size_t)DD * HH * 2;
  ushort_t* w2T  = (ushort_t*)ws; ws += (size_t)HH * DD * 2;

  k_phase0<<<512, 256, 0, stream>>>(x, xA, conv_w, w1, w2, cwT, w1T, w2T);

  // conv layers ping-pong xA <-> xB; final state lands in xB
  k_conv_fused<<<NR / 64, 256, 0, stream>>>(
      x, xA, xB, cwT, conv_b, 0, norm_g, norm_b, 0);
  k_conv_fused<<<NR / 64, 256, 0, stream>>>(
      x, xB, xA, cwT + (size_t)DD * DD, conv_b, DD, norm_g, norm_b, DD);
  k_conv_fused<<<NR / 64, 256, 0, stream>>>(
      x, xA, xB, cwT + (size_t)2 * DD * DD, conv_b, 2 * DD, norm_g, norm_b,
      2 * DD);

  // fused FFN: LN + GEMM1 + GELU + GEMM2 + residual, one launch
  k_ffn<<<NR / 64, 256, 0, stream>>>(
      x, xB, w1T, w2T, nff_g, nff_b, b1, b2, d_out);
}